// Round 4
// baseline (116.697 us; speedup 1.0000x reference)
//
#include <hip/hip_runtime.h>

// Problem constants (fixed by the reference).
#define BATCH 16384
#define DIN   128
#define HIDN  16
#define NNODE 255
#define NLEAF 256

typedef _Float16 half8 __attribute__((ext_vector_type(8)));
typedef _Float16 half4 __attribute__((ext_vector_type(4)));
typedef float   float4v __attribute__((ext_vector_type(4)));

// ---------------- combined pack kernel ----------------
// blocks 0..1023: pack x -> f16 B-operand fragments
//   lane L holds B[k=(L>>4)*8+j][n=L&15] (n=batch, k=din); ws: [bt][kc][lane] half8
// blocks 1024..1278: pack W1[n] -> f16 A-operand fragments (LDS-staged)
//   lane L holds A[m=L&15][k=(L>>4)*8+j] (m=hidden, k=din); plus W2[n] -> f16
__global__ __launch_bounds__(256) void k_pack(const float* __restrict__ x, const float* __restrict__ w1,
                                              const float* __restrict__ w2,
                                              half8* __restrict__ xp, half8* __restrict__ w1p,
                                              _Float16* __restrict__ w2h) {
    __shared__ float w[DIN * 17];
    int t = threadIdx.x;
    if (blockIdx.x < 1024) {
        int gid  = blockIdx.x * 256 + t;
        int lane = gid & 63;
        int kc   = (gid >> 6) & 3;
        int bt   = gid >> 8;
        const float4* src = (const float4*)(x + (size_t)(bt * 16 + (lane & 15)) * DIN + kc * 32 + ((lane >> 4) * 8));
        float4 v0 = src[0], v1 = src[1];
        half8 v;
        v[0] = (_Float16)v0.x; v[1] = (_Float16)v0.y; v[2] = (_Float16)v0.z; v[3] = (_Float16)v0.w;
        v[4] = (_Float16)v1.x; v[5] = (_Float16)v1.y; v[6] = (_Float16)v1.z; v[7] = (_Float16)v1.w;
        xp[gid] = v;
    } else {
        int n = blockIdx.x - 1024;
        const float4* src = (const float4*)(w1 + (size_t)n * (DIN * HIDN)) + t * 2;
        float4 a0 = src[0], a1 = src[1];
        int base = t * 8;
#pragma unroll
        for (int e = 0; e < 4; ++e) {
            int idx0 = base + e, idx1 = base + 4 + e;
            w[(idx0 >> 4) * 17 + (idx0 & 15)] = (&a0.x)[e];
            w[(idx1 >> 4) * 17 + (idx1 & 15)] = (&a1.x)[e];
        }
        __syncthreads();
        int L  = t & 63;
        int kc = t >> 6;
        int m  = L & 15;
        int k0 = kc * 32 + (L >> 4) * 8;
        half8 v;
#pragma unroll
        for (int j = 0; j < 8; ++j) v[j] = (_Float16)w[(k0 + j) * 17 + m];
        w1p[(size_t)n * 256 + t] = v;
        if (t < HIDN) w2h[n * HIDN + t] = (_Float16)w2[n * HIDN + t];
    }
}

// ---------------- fused MLP + tree kernel, 32 rows / block, 8 waves ----------------
// Grid 512 blocks x 512 threads. LDS 33.3 KB -> 2 blocks/CU -> 16 waves/CU
// (4 waves/SIMD, double round-3's TLP at identical L2 traffic: each w1p fragment
// is still read by exactly ONE wave per block).
// Phase 1 (MLP): waves split the 255 nodes round-robin (n == wv mod 8, 31-32
//   nodes/wave); each wave computes both 16-row tiles via double MFMA, writes
//   sigmoid(logit) into LDS sp[32][260]. Depth-1 operand prefetch.
// Phase 2 (tree): one barrier, each wave scans 4 rows from LDS.
__global__ __launch_bounds__(512, 4) void k_fused(const half8* __restrict__ xp, const half8* __restrict__ w1p,
                                                  const float* __restrict__ b1, const _Float16* __restrict__ w2h,
                                                  const float* __restrict__ b2, const float* __restrict__ leaf,
                                                  float* __restrict__ h_out, float* __restrict__ pp_out,
                                                  float* __restrict__ p_out, float* __restrict__ nr_out) {
    __shared__ float sp[32][260];                 // stride 260 words -> 2-way banks (free)
    int wv   = threadIdx.x >> 6;
    int lane = threadIdx.x & 63;
    int q    = lane >> 4;
    int bt0  = blockIdx.x * 2;                    // two 16-row tiles

    // B-fragments for both tiles (identical in every wave): 8 half8 = 32 VGPRs
    half8 bq[2][4];
#pragma unroll
    for (int t = 0; t < 2; ++t)
#pragma unroll
        for (int kc = 0; kc < 4; ++kc)
            bq[t][kc] = xp[(size_t)((bt0 + t) * 4 + kc) * 64 + lane];
    asm volatile("" ::: "memory");

    // ---- phase 1: MLP over this wave's nodes ----
    int cnt = (wv < 7) ? 32 : 31;                 // 255 = 7*32 + 31
    int n   = wv;
    half8 a[4];
#pragma unroll
    for (int kc = 0; kc < 4; ++kc) a[kc] = w1p[(size_t)(n * 4 + kc) * 64 + lane];
    float4 b1f = ((const float4*)(b1 + n * HIDN))[q];
    half4  a2  = *(const half4*)(w2h + n * HIDN + q * 4);
    float  b2v = b2[n];

    for (int i = 0; i < cnt; ++i) {
        int nn = n + ((i + 1 < cnt) ? 8 : 0);     // branch-free clamp
        half8 an[4];
#pragma unroll
        for (int kc = 0; kc < 4; ++kc) an[kc] = w1p[(size_t)(nn * 4 + kc) * 64 + lane];
        float4 b1n = ((const float4*)(b1 + nn * HIDN))[q];
        half4  a2n = *(const half4*)(w2h + nn * HIDN + q * 4);
        float  b2n = b2[nn];

#pragma unroll
        for (int t = 0; t < 2; ++t) {
            float4v acc = {b1f.x, b1f.y, b1f.z, b1f.w};
#pragma unroll
            for (int kc = 0; kc < 4; ++kc)
                acc = __builtin_amdgcn_mfma_f32_16x16x32_f16(a[kc], bq[t][kc], acc, 0, 0, 0);
            half4 rb;
#pragma unroll
            for (int r = 0; r < 4; ++r) rb[r] = (_Float16)fmaxf(acc[r], 0.f);
            float4v acc2 = {b2v, b2v, b2v, b2v};
            acc2 = __builtin_amdgcn_mfma_f32_16x16x16f16(a2, rb, acc2, 0, 0, 0);
            if (lane < 16)
                sp[t * 16 + lane][n] =
                    __builtin_amdgcn_rcpf(1.f + __builtin_amdgcn_exp2f(-1.44269504088896f * acc2[0]));
        }
#pragma unroll
        for (int kc = 0; kc < 4; ++kc) a[kc] = an[kc];
        b1f = b1n; a2 = a2n; b2v = b2n;
        n = nn;
    }
    __syncthreads();

    // ---- phase 2: tree scan, 4 rows per wave, straight from LDS ----
    const float4 lf = *(const float4*)(leaf + 4 * lane);
    for (int rr = 0; rr < 4; ++rr) {
        int r = wv * 4 + rr;
        int b = blockIdx.x * 32 + r;
        const float* P = &sp[r][0];
        float* nr = nr_out + (size_t)b * NNODE;

        // p_out copy, coalesced
#pragma unroll
        for (int c = 0; c < 4; ++c) {
            int idx = c * 64 + lane;
            if (idx < NNODE)
                p_out[(size_t)b * NNODE + idx] = P[idx];
        }

        float pref = 1.f;
#pragma unroll
        for (int l = 0; l < 6; ++l) {
            if ((lane & ((1 << (6 - l)) - 1)) == 0)
                nr[(1 << l) - 1 + (lane >> (6 - l))] = pref;
            float pv  = P[(1 << l) - 1 + (lane >> (6 - l))];
            int  bit  = (lane >> (5 - l)) & 1;
            pref *= bit ? pv : (1.f - pv);
        }
        nr[63 + lane] = pref;
        float p6 = P[63 + lane];
        float pl = pref * (1.f - p6);
        float pr = pref * p6;
        nr[127 + 2 * lane] = pl;
        nr[128 + 2 * lane] = pr;
        float p7a = P[127 + 2 * lane];
        float p7b = P[128 + 2 * lane];
        float4v pp;
        pp[0] = pl * (1.f - p7a);
        pp[1] = pl * p7a;
        pp[2] = pr * (1.f - p7b);
        pp[3] = pr * p7b;
        *(float4v*)(pp_out + (size_t)b * NLEAF + 4 * lane) = pp;
        float hs = pp[0] * lf.x + pp[1] * lf.y + pp[2] * lf.z + pp[3] * lf.w;
#pragma unroll
        for (int off = 1; off < 64; off <<= 1) hs += __shfl_xor(hs, off, 64);
        if (lane == 0) h_out[b] = hs;
    }
}

extern "C" void kernel_launch(void* const* d_in, const int* in_sizes, int n_in,
                              void* d_out, int out_size, void* d_ws, size_t ws_size,
                              hipStream_t stream) {
    const float* x    = (const float*)d_in[0];
    const float* W1   = (const float*)d_in[1];
    const float* b1   = (const float*)d_in[2];
    const float* W2   = (const float*)d_in[3];
    const float* b2   = (const float*)d_in[4];
    const float* leaf = (const float*)d_in[5];

    float* out    = (float*)d_out;
    float* h_out  = out;                                   // [16384]
    float* pp_out = out + BATCH;                           // [16384*256]
    float* p_out  = pp_out + (size_t)BATCH * NLEAF;        // [16384*255]
    float* nr_out = p_out + (size_t)BATCH * NNODE;         // [16384*255]

    // workspace: 4 MB xp + ~1 MB w1p + 8 KB w2h (p_ws intermediate eliminated)
    half8*    xp   = (half8*)d_ws;
    half8*    w1p  = xp + (size_t)1024 * 4 * 64;
    _Float16* w2h  = (_Float16*)(w1p + (size_t)NNODE * 256);

    hipLaunchKernelGGL(k_pack,  dim3(1024 + NNODE), dim3(256), 0, stream, x, W1, W2, xp, w1p, w2h);
    hipLaunchKernelGGL(k_fused, dim3(512),          dim3(512), 0, stream,
                       xp, w1p, b1, w2h, b2, leaf, h_out, pp_out, p_out, nr_out);
}

// Round 5
// 112.078 us; speedup vs baseline: 1.0412x; 1.0412x over previous
//
#include <hip/hip_runtime.h>

// Problem constants (fixed by the reference).
#define BATCH 16384
#define DIN   128
#define HIDN  16
#define NNODE 255
#define NLEAF 256

typedef _Float16 half8 __attribute__((ext_vector_type(8)));
typedef _Float16 half4 __attribute__((ext_vector_type(4)));
typedef float   float4v __attribute__((ext_vector_type(4)));

// ---------------- combined pack kernel ----------------
// blocks 0..1023: pack x -> f16 B-operand fragments
//   lane L holds B[k=(L>>4)*8+j][n=L&15] (n=batch, k=din); ws: [bt][kc][lane] half8
// blocks 1024..1278: pack W1[n] -> f16 A-operand fragments (LDS-staged)
//   lane L holds A[m=L&15][k=(L>>4)*8+j] (m=hidden, k=din); plus W2[n] -> f16
__global__ __launch_bounds__(256) void k_pack(const float* __restrict__ x, const float* __restrict__ w1,
                                              const float* __restrict__ w2,
                                              half8* __restrict__ xp, half8* __restrict__ w1p,
                                              _Float16* __restrict__ w2h) {
    __shared__ float w[DIN * 17];
    int t = threadIdx.x;
    if (blockIdx.x < 1024) {
        int gid  = blockIdx.x * 256 + t;
        int lane = gid & 63;
        int kc   = (gid >> 6) & 3;
        int bt   = gid >> 8;
        const float4* src = (const float4*)(x + (size_t)(bt * 16 + (lane & 15)) * DIN + kc * 32 + ((lane >> 4) * 8));
        float4 v0 = src[0], v1 = src[1];
        half8 v;
        v[0] = (_Float16)v0.x; v[1] = (_Float16)v0.y; v[2] = (_Float16)v0.z; v[3] = (_Float16)v0.w;
        v[4] = (_Float16)v1.x; v[5] = (_Float16)v1.y; v[6] = (_Float16)v1.z; v[7] = (_Float16)v1.w;
        xp[gid] = v;
    } else {
        int n = blockIdx.x - 1024;
        const float4* src = (const float4*)(w1 + (size_t)n * (DIN * HIDN)) + t * 2;
        float4 a0 = src[0], a1 = src[1];
        int base = t * 8;
#pragma unroll
        for (int e = 0; e < 4; ++e) {
            int idx0 = base + e, idx1 = base + 4 + e;
            w[(idx0 >> 4) * 17 + (idx0 & 15)] = (&a0.x)[e];
            w[(idx1 >> 4) * 17 + (idx1 & 15)] = (&a1.x)[e];
        }
        __syncthreads();
        int L  = t & 63;
        int kc = t >> 6;
        int m  = L & 15;
        int k0 = kc * 32 + (L >> 4) * 8;
        half8 v;
#pragma unroll
        for (int j = 0; j < 8; ++j) v[j] = (_Float16)w[(k0 + j) * 17 + m];
        w1p[(size_t)n * 256 + t] = v;
        if (t < HIDN) w2h[n * HIDN + t] = (_Float16)w2[n * HIDN + t];
    }
}

// ---------------- fused MLP + tree kernel, 64 rows / block, 8 waves ----------------
// Grid 256 blocks (1/CU) x 512 threads. LDS 66.6 KB. Theory: kernel is bound by
// per-CU vector-memory (TA/L1 ~64B/cyc) throughput, dominated by w1p fragment
// streaming; TLP-doubling at constant bytes/CU gave exactly 0 (round 4). 64 rows
// amortize each node's 4.25 KB fragment load over 4 row-tiles and 1 block/CU cuts
// w1p per-CU traffic to 1 MB (vs 2 MB in rounds 3-4).
// __launch_bounds__(512,2): 256-VGPR budget so bq[4][4] (64 VGPR) + double-buffered
// operands stay register-resident (round 2's 128-VGPR cap spilled them).
// Phase 1: waves split nodes mod 8 (~32/wave); 4 independent tile chains = ILP.
// Phase 2: one barrier, each wave scans 8 rows from LDS.
__global__ __launch_bounds__(512, 2) void k_fused(const half8* __restrict__ xp, const half8* __restrict__ w1p,
                                                  const float* __restrict__ b1, const _Float16* __restrict__ w2h,
                                                  const float* __restrict__ b2, const float* __restrict__ leaf,
                                                  float* __restrict__ h_out, float* __restrict__ pp_out,
                                                  float* __restrict__ p_out, float* __restrict__ nr_out) {
    __shared__ float sp[64][260];                 // 66.6 KB, stride 260 words
    int wv   = threadIdx.x >> 6;
    int lane = threadIdx.x & 63;
    int q    = lane >> 4;
    int bt0  = blockIdx.x * 4;                    // four 16-row tiles

    // B-fragments for all 4 tiles (identical in every wave): 16 half8 = 64 VGPRs
    half8 bq[4][4];
#pragma unroll
    for (int t = 0; t < 4; ++t)
#pragma unroll
        for (int kc = 0; kc < 4; ++kc)
            bq[t][kc] = xp[(size_t)((bt0 + t) * 4 + kc) * 64 + lane];
    asm volatile("" ::: "memory");

    // ---- phase 1: MLP over this wave's nodes (n == wv mod 8) ----
    int cnt = (wv < 7) ? 32 : 31;                 // 255 = 7*32 + 31
    int n   = wv;
    half8 a[4];
#pragma unroll
    for (int kc = 0; kc < 4; ++kc) a[kc] = w1p[(size_t)(n * 4 + kc) * 64 + lane];
    float4 b1f = ((const float4*)(b1 + n * HIDN))[q];
    half4  a2  = *(const half4*)(w2h + n * HIDN + q * 4);
    float  b2v = b2[n];

    for (int i = 0; i < cnt; ++i) {
        int nn = n + ((i + 1 < cnt) ? 8 : 0);     // branch-free clamp
        half8 an[4];
#pragma unroll
        for (int kc = 0; kc < 4; ++kc) an[kc] = w1p[(size_t)(nn * 4 + kc) * 64 + lane];
        float4 b1n = ((const float4*)(b1 + nn * HIDN))[q];
        half4  a2n = *(const half4*)(w2h + nn * HIDN + q * 4);
        float  b2n = b2[nn];

#pragma unroll
        for (int t = 0; t < 4; ++t) {
            float4v acc = {b1f.x, b1f.y, b1f.z, b1f.w};
#pragma unroll
            for (int kc = 0; kc < 4; ++kc)
                acc = __builtin_amdgcn_mfma_f32_16x16x32_f16(a[kc], bq[t][kc], acc, 0, 0, 0);
            half4 rb;
#pragma unroll
            for (int r = 0; r < 4; ++r) rb[r] = (_Float16)fmaxf(acc[r], 0.f);
            float4v acc2 = {b2v, b2v, b2v, b2v};
            acc2 = __builtin_amdgcn_mfma_f32_16x16x16f16(a2, rb, acc2, 0, 0, 0);
            if (lane < 16)
                sp[t * 16 + lane][n] =
                    __builtin_amdgcn_rcpf(1.f + __builtin_amdgcn_exp2f(-1.44269504088896f * acc2[0]));
        }
#pragma unroll
        for (int kc = 0; kc < 4; ++kc) a[kc] = an[kc];
        b1f = b1n; a2 = a2n; b2v = b2n;
        n = nn;
    }
    __syncthreads();

    // ---- phase 2: tree scan, 8 rows per wave, straight from LDS ----
    const float4 lf = *(const float4*)(leaf + 4 * lane);
    for (int rr = 0; rr < 8; ++rr) {
        int r = wv * 8 + rr;
        int b = blockIdx.x * 64 + r;
        const float* P = &sp[r][0];
        float* nr = nr_out + (size_t)b * NNODE;

        // p_out copy, coalesced
#pragma unroll
        for (int c = 0; c < 4; ++c) {
            int idx = c * 64 + lane;
            if (idx < NNODE)
                p_out[(size_t)b * NNODE + idx] = P[idx];
        }

        float pref = 1.f;
#pragma unroll
        for (int l = 0; l < 6; ++l) {
            if ((lane & ((1 << (6 - l)) - 1)) == 0)
                nr[(1 << l) - 1 + (lane >> (6 - l))] = pref;
            float pv  = P[(1 << l) - 1 + (lane >> (6 - l))];
            int  bit  = (lane >> (5 - l)) & 1;
            pref *= bit ? pv : (1.f - pv);
        }
        nr[63 + lane] = pref;
        float p6 = P[63 + lane];
        float pl = pref * (1.f - p6);
        float pr = pref * p6;
        nr[127 + 2 * lane] = pl;
        nr[128 + 2 * lane] = pr;
        float p7a = P[127 + 2 * lane];
        float p7b = P[128 + 2 * lane];
        float4v pp;
        pp[0] = pl * (1.f - p7a);
        pp[1] = pl * p7a;
        pp[2] = pr * (1.f - p7b);
        pp[3] = pr * p7b;
        *(float4v*)(pp_out + (size_t)b * NLEAF + 4 * lane) = pp;
        float hs = pp[0] * lf.x + pp[1] * lf.y + pp[2] * lf.z + pp[3] * lf.w;
#pragma unroll
        for (int off = 1; off < 64; off <<= 1) hs += __shfl_xor(hs, off, 64);
        if (lane == 0) h_out[b] = hs;
    }
}

extern "C" void kernel_launch(void* const* d_in, const int* in_sizes, int n_in,
                              void* d_out, int out_size, void* d_ws, size_t ws_size,
                              hipStream_t stream) {
    const float* x    = (const float*)d_in[0];
    const float* W1   = (const float*)d_in[1];
    const float* b1   = (const float*)d_in[2];
    const float* W2   = (const float*)d_in[3];
    const float* b2   = (const float*)d_in[4];
    const float* leaf = (const float*)d_in[5];

    float* out    = (float*)d_out;
    float* h_out  = out;                                   // [16384]
    float* pp_out = out + BATCH;                           // [16384*256]
    float* p_out  = pp_out + (size_t)BATCH * NLEAF;        // [16384*255]
    float* nr_out = p_out + (size_t)BATCH * NNODE;         // [16384*255]

    // workspace: 4 MB xp + ~1 MB w1p + 8 KB w2h (p_ws intermediate eliminated)
    half8*    xp   = (half8*)d_ws;
    half8*    w1p  = xp + (size_t)1024 * 4 * 64;
    _Float16* w2h  = (_Float16*)(w1p + (size_t)NNODE * 256);

    hipLaunchKernelGGL(k_pack,  dim3(1024 + NNODE), dim3(256), 0, stream, x, W1, W2, xp, w1p, w2h);
    hipLaunchKernelGGL(k_fused, dim3(256),          dim3(512), 0, stream,
                       xp, w1p, b1, w2h, b2, leaf, h_out, pp_out, p_out, nr_out);
}

// Round 7
// 107.170 us; speedup vs baseline: 1.0889x; 1.0458x over previous
//
#include <hip/hip_runtime.h>

// Problem constants (fixed by the reference).
#define BATCH 16384
#define DIN   128
#define HIDN  16
#define NNODE 255
#define NLEAF 256

typedef _Float16 half8 __attribute__((ext_vector_type(8)));
typedef float   float4v __attribute__((ext_vector_type(4)));

// ---------------- combined pack kernel ----------------
// blocks 0..1023: pack x -> f16 B-operand fragments
//   lane L holds B[k=(L>>4)*8+j][n=L&15] (n=batch, k=din); ws: [bt][kc][lane] half8
// blocks 1024..1278: pack W1[n] -> f16 A-operand fragments (LDS-staged)
//   lane L holds A[m=L&15][k=(L>>4)*8+j] (m=hidden, k=din)
__global__ __launch_bounds__(256) void k_pack(const float* __restrict__ x, const float* __restrict__ w1,
                                              half8* __restrict__ xp, half8* __restrict__ w1p) {
    __shared__ float w[DIN * 17];
    int t = threadIdx.x;
    if (blockIdx.x < 1024) {
        int gid  = blockIdx.x * 256 + t;
        int lane = gid & 63;
        int kc   = (gid >> 6) & 3;
        int bt   = gid >> 8;
        const float4* src = (const float4*)(x + (size_t)(bt * 16 + (lane & 15)) * DIN + kc * 32 + ((lane >> 4) * 8));
        float4 v0 = src[0], v1 = src[1];
        half8 v;
        v[0] = (_Float16)v0.x; v[1] = (_Float16)v0.y; v[2] = (_Float16)v0.z; v[3] = (_Float16)v0.w;
        v[4] = (_Float16)v1.x; v[5] = (_Float16)v1.y; v[6] = (_Float16)v1.z; v[7] = (_Float16)v1.w;
        xp[gid] = v;
    } else {
        int n = blockIdx.x - 1024;
        const float4* src = (const float4*)(w1 + (size_t)n * (DIN * HIDN)) + t * 2;
        float4 a0 = src[0], a1 = src[1];
        int base = t * 8;
#pragma unroll
        for (int e = 0; e < 4; ++e) {
            int idx0 = base + e, idx1 = base + 4 + e;
            w[(idx0 >> 4) * 17 + (idx0 & 15)] = (&a0.x)[e];
            w[(idx1 >> 4) * 17 + (idx1 & 15)] = (&a1.x)[e];
        }
        __syncthreads();
        int L  = t & 63;
        int kc = t >> 6;
        int m  = L & 15;
        int k0 = kc * 32 + (L >> 4) * 8;
        half8 v;
#pragma unroll
        for (int j = 0; j < 8; ++j) v[j] = (_Float16)w[(k0 + j) * 17 + m];
        w1p[(size_t)n * 256 + t] = v;
    }
}

// ---------------- fused MLP + tree kernel, 64 rows / block, 8 waves ----------------
// Grid 256 blocks (1/CU) x 512 threads, LDS 66.6 KB. Counters (R3-R5) showed the
// kernel is VALU-ISSUE bound (VALUBusy 46% >> MfmaUtil 18%; time invariant under
// TLP-doubling at constant per-CU work). This version cuts phase-1 issue count:
//  - layer-2 via f32 relu-FMA + 3-shuffle butterfly transpose-reduce instead of a
//    broadcast MFMA (removes f16 repack, 16 acc2-init movs, 4 masked LDS stores;
//    sigmoid now useful on all 64 lanes; one full-wave LDS store per node)
//  - uniform 32-trip node loop (clamp-to-254 dummy for wv7; identical-value LDS
//    double-write is benign) with explicit 2-body ping-pong: zero rotation movs.
__global__ __launch_bounds__(512, 2) void k_fused(const half8* __restrict__ xp, const half8* __restrict__ w1p,
                                                  const float* __restrict__ b1, const float* __restrict__ w2,
                                                  const float* __restrict__ b2, const float* __restrict__ leaf,
                                                  float* __restrict__ h_out, float* __restrict__ pp_out,
                                                  float* __restrict__ p_out, float* __restrict__ nr_out) {
    __shared__ float sp[64][260];                 // 66.6 KB
    int wv   = threadIdx.x >> 6;
    int lane = threadIdx.x & 63;
    int q    = lane >> 4;
    int bt0  = blockIdx.x * 4;                    // four 16-row tiles

    // B-fragments for all 4 tiles (identical in every wave): 16 half8 = 64 VGPRs
    half8 bq[4][4];
#pragma unroll
    for (int t = 0; t < 4; ++t)
#pragma unroll
        for (int kc = 0; kc < 4; ++kc)
            bq[t][kc] = xp[(size_t)((bt0 + t) * 4 + kc) * 64 + lane];
    asm volatile("" ::: "memory");

    // ---- phase 1: MLP over this wave's nodes (n == wv mod 8), ping-pong ----
    half8  aA[4], aB[4];
    float4 b1A, b1B, w2A, w2B;
    float  b2A, b2B;

    int nA = wv;
#pragma unroll
    for (int kc = 0; kc < 4; ++kc) aA[kc] = w1p[(size_t)(nA * 4 + kc) * 64 + lane];
    b1A = ((const float4*)(b1 + nA * HIDN))[q];
    w2A = ((const float4*)(w2 + nA * HIDN))[q];
    b2A = b2[nA];
    {
        int nB = nA + 8;
#pragma unroll
        for (int kc = 0; kc < 4; ++kc) aB[kc] = w1p[(size_t)(nB * 4 + kc) * 64 + lane];
        b1B = ((const float4*)(b1 + nB * HIDN))[q];
        w2B = ((const float4*)(w2 + nB * HIDN))[q];
        b2B = b2[nB];
    }

// One node: 16 MFMA -> f32 relu-FMA partials -> prefetch -> butterfly -> sigmoid -> LDS.
// Butterfly: lane(q,b) ends with logit of tile t==q, batch row q*16+b == lane.
#define MLP_BODY(AS, B1S, W2S, B2S, NODE, PREN)                                            \
    do {                                                                                   \
        float4v acc0 = {B1S.x, B1S.y, B1S.z, B1S.w};                                       \
        float4v acc1 = acc0, acc2 = acc0, acc3 = acc0;                                     \
        _Pragma("unroll") for (int kc = 0; kc < 4; ++kc) {                                 \
            acc0 = __builtin_amdgcn_mfma_f32_16x16x32_f16(AS[kc], bq[0][kc], acc0, 0, 0, 0);\
            acc1 = __builtin_amdgcn_mfma_f32_16x16x32_f16(AS[kc], bq[1][kc], acc1, 0, 0, 0);\
            acc2 = __builtin_amdgcn_mfma_f32_16x16x32_f16(AS[kc], bq[2][kc], acc2, 0, 0, 0);\
            acc3 = __builtin_amdgcn_mfma_f32_16x16x32_f16(AS[kc], bq[3][kc], acc3, 0, 0, 0);\
        }                                                                                  \
        float s0 = fmaf(fmaxf(acc0[0], 0.f), W2S.x, fmaf(fmaxf(acc0[1], 0.f), W2S.y,       \
                   fmaf(fmaxf(acc0[2], 0.f), W2S.z, fmaxf(acc0[3], 0.f) * W2S.w)));        \
        float s1 = fmaf(fmaxf(acc1[0], 0.f), W2S.x, fmaf(fmaxf(acc1[1], 0.f), W2S.y,       \
                   fmaf(fmaxf(acc1[2], 0.f), W2S.z, fmaxf(acc1[3], 0.f) * W2S.w)));        \
        float s2 = fmaf(fmaxf(acc2[0], 0.f), W2S.x, fmaf(fmaxf(acc2[1], 0.f), W2S.y,       \
                   fmaf(fmaxf(acc2[2], 0.f), W2S.z, fmaxf(acc2[3], 0.f) * W2S.w)));        \
        float s3 = fmaf(fmaxf(acc3[0], 0.f), W2S.x, fmaf(fmaxf(acc3[1], 0.f), W2S.y,       \
                   fmaf(fmaxf(acc3[2], 0.f), W2S.z, fmaxf(acc3[3], 0.f) * W2S.w)));        \
        float b2c = B2S;                                                                   \
        _Pragma("unroll") for (int kc = 0; kc < 4; ++kc)                                   \
            AS[kc] = w1p[(size_t)((PREN) * 4 + kc) * 64 + lane];                           \
        B1S = ((const float4*)(b1 + (PREN) * HIDN))[q];                                    \
        W2S = ((const float4*)(w2 + (PREN) * HIDN))[q];                                    \
        B2S = b2[PREN];                                                                    \
        int q1 = q & 1, q2 = q & 2;                                                        \
        float a01 = q1 ? s1 : s0, c01 = q1 ? s0 : s1;                                      \
        a01 += __shfl_xor(c01, 16, 64);                                                    \
        float a23 = q1 ? s3 : s2, c23 = q1 ? s2 : s3;                                      \
        a23 += __shfl_xor(c23, 16, 64);                                                    \
        float e = q2 ? a23 : a01, f = q2 ? a01 : a23;                                      \
        e += __shfl_xor(f, 32, 64);                                                        \
        float lg = e + b2c;                                                                \
        sp[lane][NODE] =                                                                   \
            __builtin_amdgcn_rcpf(1.f + __builtin_amdgcn_exp2f(-1.44269504088896f * lg));  \
    } while (0)

    for (int ii = 0; ii < 16; ++ii) {
        int pA = nA + 16; pA = pA > 254 ? 254 : pA;
        MLP_BODY(aA, b1A, w2A, b2A, nA, pA);
        int nB = nA + 8;  nB = nB > 254 ? 254 : nB;   // wv7 last: dup of node 254 (benign)
        int pB = nA + 24; pB = pB > 254 ? 254 : pB;
        MLP_BODY(aB, b1B, w2B, b2B, nB, pB);
        nA += 16;
    }
#undef MLP_BODY
    __syncthreads();

    // ---- phase 2: tree scan, 8 rows per wave, straight from LDS ----
    const float4 lf = *(const float4*)(leaf + 4 * lane);
    for (int rr = 0; rr < 8; ++rr) {
        int r = wv * 8 + rr;
        int b = blockIdx.x * 64 + r;
        const float* P = &sp[r][0];
        float* nr = nr_out + (size_t)b * NNODE;

        // p_out copy, coalesced
#pragma unroll
        for (int c = 0; c < 4; ++c) {
            int idx = c * 64 + lane;
            if (idx < NNODE)
                p_out[(size_t)b * NNODE + idx] = P[idx];
        }

        float pref = 1.f;
#pragma unroll
        for (int l = 0; l < 6; ++l) {
            if ((lane & ((1 << (6 - l)) - 1)) == 0)
                nr[(1 << l) - 1 + (lane >> (6 - l))] = pref;
            float pv  = P[(1 << l) - 1 + (lane >> (6 - l))];
            int  bit  = (lane >> (5 - l)) & 1;
            pref *= bit ? pv : (1.f - pv);
        }
        nr[63 + lane] = pref;
        float p6 = P[63 + lane];
        float pl = pref * (1.f - p6);
        float pr = pref * p6;
        nr[127 + 2 * lane] = pl;
        nr[128 + 2 * lane] = pr;
        float p7a = P[127 + 2 * lane];
        float p7b = P[128 + 2 * lane];
        float4v pp;
        pp[0] = pl * (1.f - p7a);
        pp[1] = pl * p7a;
        pp[2] = pr * (1.f - p7b);
        pp[3] = pr * p7b;
        *(float4v*)(pp_out + (size_t)b * NLEAF + 4 * lane) = pp;
        float hs = pp[0] * lf.x + pp[1] * lf.y + pp[2] * lf.z + pp[3] * lf.w;
#pragma unroll
        for (int off = 1; off < 64; off <<= 1) hs += __shfl_xor(hs, off, 64);
        if (lane == 0) h_out[b] = hs;
    }
}

extern "C" void kernel_launch(void* const* d_in, const int* in_sizes, int n_in,
                              void* d_out, int out_size, void* d_ws, size_t ws_size,
                              hipStream_t stream) {
    const float* x    = (const float*)d_in[0];
    const float* W1   = (const float*)d_in[1];
    const float* b1   = (const float*)d_in[2];
    const float* W2   = (const float*)d_in[3];
    const float* b2   = (const float*)d_in[4];
    const float* leaf = (const float*)d_in[5];

    float* out    = (float*)d_out;
    float* h_out  = out;                                   // [16384]
    float* pp_out = out + BATCH;                           // [16384*256]
    float* p_out  = pp_out + (size_t)BATCH * NLEAF;        // [16384*255]
    float* nr_out = p_out + (size_t)BATCH * NNODE;         // [16384*255]

    // workspace: 4 MB xp + ~1 MB w1p
    half8* xp  = (half8*)d_ws;
    half8* w1p = xp + (size_t)1024 * 4 * 64;

    hipLaunchKernelGGL(k_pack,  dim3(1024 + NNODE), dim3(256), 0, stream, x, W1, xp, w1p);
    hipLaunchKernelGGL(k_fused, dim3(256),          dim3(512), 0, stream,
                       xp, w1p, b1, W2, b2, leaf, h_out, pp_out, p_out, nr_out);
}

// Round 8
// 106.583 us; speedup vs baseline: 1.0949x; 1.0055x over previous
//
#include <hip/hip_runtime.h>

// Problem constants (fixed by the reference).
#define BATCH 16384
#define DIN   128
#define HIDN  16
#define NNODE 255
#define NLEAF 256

typedef _Float16 half8 __attribute__((ext_vector_type(8)));
typedef float   float4v __attribute__((ext_vector_type(4)));

// ---------------- combined pack kernel ----------------
// blocks 0..1023: pack x -> f16 B-operand fragments
//   lane L holds B[k=(L>>4)*8+j][n=L&15] (n=batch, k=din); ws: [bt][kc][lane] half8
// blocks 1024..1278: pack W1[n] -> f16 A-operand fragments (LDS-staged)
//   lane L holds A[m=L&15][k=(L>>4)*8+j] (m=hidden, k=din)
__global__ __launch_bounds__(256) void k_pack(const float* __restrict__ x, const float* __restrict__ w1,
                                              half8* __restrict__ xp, half8* __restrict__ w1p) {
    __shared__ float w[DIN * 17];
    int t = threadIdx.x;
    if (blockIdx.x < 1024) {
        int gid  = blockIdx.x * 256 + t;
        int lane = gid & 63;
        int kc   = (gid >> 6) & 3;
        int bt   = gid >> 8;
        const float4* src = (const float4*)(x + (size_t)(bt * 16 + (lane & 15)) * DIN + kc * 32 + ((lane >> 4) * 8));
        float4 v0 = src[0], v1 = src[1];
        half8 v;
        v[0] = (_Float16)v0.x; v[1] = (_Float16)v0.y; v[2] = (_Float16)v0.z; v[3] = (_Float16)v0.w;
        v[4] = (_Float16)v1.x; v[5] = (_Float16)v1.y; v[6] = (_Float16)v1.z; v[7] = (_Float16)v1.w;
        xp[gid] = v;
    } else {
        int n = blockIdx.x - 1024;
        const float4* src = (const float4*)(w1 + (size_t)n * (DIN * HIDN)) + t * 2;
        float4 a0 = src[0], a1 = src[1];
        int base = t * 8;
#pragma unroll
        for (int e = 0; e < 4; ++e) {
            int idx0 = base + e, idx1 = base + 4 + e;
            w[(idx0 >> 4) * 17 + (idx0 & 15)] = (&a0.x)[e];
            w[(idx1 >> 4) * 17 + (idx1 & 15)] = (&a1.x)[e];
        }
        __syncthreads();
        int L  = t & 63;
        int kc = t >> 6;
        int m  = L & 15;
        int k0 = kc * 32 + (L >> 4) * 8;
        half8 v;
#pragma unroll
        for (int j = 0; j < 8; ++j) v[j] = (_Float16)w[(k0 + j) * 17 + m];
        w1p[(size_t)n * 256 + t] = v;
    }
}

// ---------------- fused MLP + tree kernel, 64 rows / block, 12 waves ----------------
// Grid 256 blocks (1/CU) x 768 threads = 12 waves = 3 waves/SIMD. Per-CU w1p
// traffic stays ~1 MB (each fragment read by exactly one wave); LDS 66.6 KB.
// R7 post-mortem: all pipes <50% at 2 w/SIMD -> exposed per-node dependency chain
// (MFMA x4 -> relu/fma -> 3 dependent shuffles -> exp/rcp), ~300 cyc vs ~220 cyc
// of issue work. 3 w/SIMD adds latency hiding at ZERO added memory cost (the R4
// "occupancy null" was measured on the old fat body with VGPR=52, i.e. operand
// rematerialization - not transferable). Waves split nodes mod 12 (<=1 clamped
// duplicate node per wave; dup LDS writes are bitwise identical -> benign).
__global__ __launch_bounds__(768, 3) void k_fused(const half8* __restrict__ xp, const half8* __restrict__ w1p,
                                                  const float* __restrict__ b1, const float* __restrict__ w2,
                                                  const float* __restrict__ b2, const float* __restrict__ leaf,
                                                  float* __restrict__ h_out, float* __restrict__ pp_out,
                                                  float* __restrict__ p_out, float* __restrict__ nr_out) {
    __shared__ float sp[64][260];                 // 66.6 KB
    int wv   = threadIdx.x >> 6;                  // 0..11
    int lane = threadIdx.x & 63;
    int q    = lane >> 4;
    int bt0  = blockIdx.x * 4;                    // four 16-row tiles

    // B-fragments for all 4 tiles (identical in every wave): 16 half8 = 64 VGPRs
    half8 bq[4][4];
#pragma unroll
    for (int t = 0; t < 4; ++t)
#pragma unroll
        for (int kc = 0; kc < 4; ++kc)
            bq[t][kc] = xp[(size_t)((bt0 + t) * 4 + kc) * 64 + lane];
    asm volatile("" ::: "memory");

    // ---- phase 1: MLP over this wave's nodes (n == wv mod 12), ping-pong ----
    half8  aA[4], aB[4];
    float4 b1A, b1B, w2A, w2B;
    float  b2A, b2B;

    int nA = wv;
#pragma unroll
    for (int kc = 0; kc < 4; ++kc) aA[kc] = w1p[(size_t)(nA * 4 + kc) * 64 + lane];
    b1A = ((const float4*)(b1 + nA * HIDN))[q];
    w2A = ((const float4*)(w2 + nA * HIDN))[q];
    b2A = b2[nA];
    {
        int nB = nA + 12;
#pragma unroll
        for (int kc = 0; kc < 4; ++kc) aB[kc] = w1p[(size_t)(nB * 4 + kc) * 64 + lane];
        b1B = ((const float4*)(b1 + nB * HIDN))[q];
        w2B = ((const float4*)(w2 + nB * HIDN))[q];
        b2B = b2[nB];
    }

// One node: 16 MFMA -> f32 relu-FMA partials -> prefetch -> butterfly -> sigmoid -> LDS.
// Butterfly: lane(q,b) ends with logit of tile t==q, batch row q*16+b == lane.
#define MLP_BODY(AS, B1S, W2S, B2S, NODE, PREN)                                            \
    do {                                                                                   \
        float4v acc0 = {B1S.x, B1S.y, B1S.z, B1S.w};                                       \
        float4v acc1 = acc0, acc2 = acc0, acc3 = acc0;                                     \
        _Pragma("unroll") for (int kc = 0; kc < 4; ++kc) {                                 \
            acc0 = __builtin_amdgcn_mfma_f32_16x16x32_f16(AS[kc], bq[0][kc], acc0, 0, 0, 0);\
            acc1 = __builtin_amdgcn_mfma_f32_16x16x32_f16(AS[kc], bq[1][kc], acc1, 0, 0, 0);\
            acc2 = __builtin_amdgcn_mfma_f32_16x16x32_f16(AS[kc], bq[2][kc], acc2, 0, 0, 0);\
            acc3 = __builtin_amdgcn_mfma_f32_16x16x32_f16(AS[kc], bq[3][kc], acc3, 0, 0, 0);\
        }                                                                                  \
        float s0 = fmaf(fmaxf(acc0[0], 0.f), W2S.x, fmaf(fmaxf(acc0[1], 0.f), W2S.y,       \
                   fmaf(fmaxf(acc0[2], 0.f), W2S.z, fmaxf(acc0[3], 0.f) * W2S.w)));        \
        float s1 = fmaf(fmaxf(acc1[0], 0.f), W2S.x, fmaf(fmaxf(acc1[1], 0.f), W2S.y,       \
                   fmaf(fmaxf(acc1[2], 0.f), W2S.z, fmaxf(acc1[3], 0.f) * W2S.w)));        \
        float s2 = fmaf(fmaxf(acc2[0], 0.f), W2S.x, fmaf(fmaxf(acc2[1], 0.f), W2S.y,       \
                   fmaf(fmaxf(acc2[2], 0.f), W2S.z, fmaxf(acc2[3], 0.f) * W2S.w)));        \
        float s3 = fmaf(fmaxf(acc3[0], 0.f), W2S.x, fmaf(fmaxf(acc3[1], 0.f), W2S.y,       \
                   fmaf(fmaxf(acc3[2], 0.f), W2S.z, fmaxf(acc3[3], 0.f) * W2S.w)));        \
        float b2c = B2S;                                                                   \
        _Pragma("unroll") for (int kc = 0; kc < 4; ++kc)                                   \
            AS[kc] = w1p[(size_t)((PREN) * 4 + kc) * 64 + lane];                           \
        B1S = ((const float4*)(b1 + (PREN) * HIDN))[q];                                    \
        W2S = ((const float4*)(w2 + (PREN) * HIDN))[q];                                    \
        B2S = b2[PREN];                                                                    \
        int q1 = q & 1, q2 = q & 2;                                                        \
        float a01 = q1 ? s1 : s0, c01 = q1 ? s0 : s1;                                      \
        a01 += __shfl_xor(c01, 16, 64);                                                    \
        float a23 = q1 ? s3 : s2, c23 = q1 ? s2 : s3;                                      \
        a23 += __shfl_xor(c23, 16, 64);                                                    \
        float e = q2 ? a23 : a01, f = q2 ? a01 : a23;                                      \
        e += __shfl_xor(f, 32, 64);                                                        \
        float lg = e + b2c;                                                                \
        sp[lane][NODE] =                                                                   \
            __builtin_amdgcn_rcpf(1.f + __builtin_amdgcn_exp2f(-1.44269504088896f * lg));  \
    } while (0)

    // 11 ping-pong iterations cover nodes {wv + 12j, j=0..21}; indices past 254
    // clamp to 254 (recomputed with node-254's own operands -> identical value).
    for (int ii = 0; ii < 11; ++ii) {
        int pA = nA + 24; pA = pA > 254 ? 254 : pA;   // next A-body node
        MLP_BODY(aA, b1A, w2A, b2A, nA, pA);          // nA <= 251 always
        int nB = nA + 12; nB = nB > 254 ? 254 : nB;   // this B-body node
        int pB = nA + 36; pB = pB > 254 ? 254 : pB;   // next B-body node
        MLP_BODY(aB, b1B, w2B, b2B, nB, pB);
        nA += 24;
    }
#undef MLP_BODY
    __syncthreads();

    // ---- phase 2: tree scan, rows r = wv, wv+12, ... straight from LDS ----
    const float4 lf = *(const float4*)(leaf + 4 * lane);
    for (int r = wv; r < 64; r += 12) {
        int b = blockIdx.x * 64 + r;
        const float* P = &sp[r][0];
        float* nr = nr_out + (size_t)b * NNODE;

        // p_out copy, coalesced
#pragma unroll
        for (int c = 0; c < 4; ++c) {
            int idx = c * 64 + lane;
            if (idx < NNODE)
                p_out[(size_t)b * NNODE + idx] = P[idx];
        }

        float pref = 1.f;
#pragma unroll
        for (int l = 0; l < 6; ++l) {
            if ((lane & ((1 << (6 - l)) - 1)) == 0)
                nr[(1 << l) - 1 + (lane >> (6 - l))] = pref;
            float pv  = P[(1 << l) - 1 + (lane >> (6 - l))];
            int  bit  = (lane >> (5 - l)) & 1;
            pref *= bit ? pv : (1.f - pv);
        }
        nr[63 + lane] = pref;
        float p6 = P[63 + lane];
        float pl = pref * (1.f - p6);
        float pr = pref * p6;
        nr[127 + 2 * lane] = pl;
        nr[128 + 2 * lane] = pr;
        float p7a = P[127 + 2 * lane];
        float p7b = P[128 + 2 * lane];
        float4v pp;
        pp[0] = pl * (1.f - p7a);
        pp[1] = pl * p7a;
        pp[2] = pr * (1.f - p7b);
        pp[3] = pr * p7b;
        *(float4v*)(pp_out + (size_t)b * NLEAF + 4 * lane) = pp;
        float hs = pp[0] * lf.x + pp[1] * lf.y + pp[2] * lf.z + pp[3] * lf.w;
#pragma unroll
        for (int off = 1; off < 64; off <<= 1) hs += __shfl_xor(hs, off, 64);
        if (lane == 0) h_out[b] = hs;
    }
}

extern "C" void kernel_launch(void* const* d_in, const int* in_sizes, int n_in,
                              void* d_out, int out_size, void* d_ws, size_t ws_size,
                              hipStream_t stream) {
    const float* x    = (const float*)d_in[0];
    const float* W1   = (const float*)d_in[1];
    const float* b1   = (const float*)d_in[2];
    const float* W2   = (const float*)d_in[3];
    const float* b2   = (const float*)d_in[4];
    const float* leaf = (const float*)d_in[5];

    float* out    = (float*)d_out;
    float* h_out  = out;                                   // [16384]
    float* pp_out = out + BATCH;                           // [16384*256]
    float* p_out  = pp_out + (size_t)BATCH * NLEAF;        // [16384*255]
    float* nr_out = p_out + (size_t)BATCH * NNODE;         // [16384*255]

    // workspace: 4 MB xp + ~1 MB w1p
    half8* xp  = (half8*)d_ws;
    half8* w1p = xp + (size_t)1024 * 4 * 64;

    hipLaunchKernelGGL(k_pack,  dim3(1024 + NNODE), dim3(256), 0, stream, x, W1, xp, w1p);
    hipLaunchKernelGGL(k_fused, dim3(256),          dim3(768), 0, stream,
                       xp, w1p, b1, W2, b2, leaf, h_out, pp_out, p_out, nr_out);
}